// Round 6
// baseline (878.381 us; speedup 1.0000x reference)
//
#include <hip/hip_runtime.h>
#include <hip/hip_cooperative_groups.h>
#include <cstdint>
#include <cstddef>

namespace cg = cooperative_groups;

#define DIN 512
#define DH  96
#define DOUT 40
#define NBLK 512
#define TPB  256
#define NTHR (NBLK * TPB)
#define NWAVE (NTHR / 64)

typedef __attribute__((ext_vector_type(8))) short s8v;
typedef __attribute__((ext_vector_type(4))) float f4v;

__device__ __forceinline__ ushort f2bf(float f) {
    uint u = __float_as_uint(f);
    u += 0x7fffu + ((u >> 16) & 1u);   // RNE
    return (ushort)(u >> 16);
}
__device__ __forceinline__ float bflo(uint u) { return __uint_as_float(u << 16); }
__device__ __forceinline__ float bfhi(uint u) { return __uint_as_float(u & 0xffff0000u); }

struct Params {
    const float* x; const int* src; const int* dst;
    const float* W1; const float* b1; const float* W2; const float* b2;
    ushort* hs1; ushort* h1; float* hs2; float* dinv;
    ushort* W1T; ushort* W2T;
    int* cnt; int* cursor; int* row_ptr; int* adj; int* bsum; int* boff;
    float* out; float* lsm;
    int N; int E;
};

// ===================== cooperative megakernel =====================
__global__ void __launch_bounds__(TPB, 2) k_mega(Params p) {
    cg::grid_group grid = cg::this_grid();
    __shared__ __align__(16) ushort lds[28672];   // 57344 B, reused across phases
    int* ldsI = (int*)lds;

    const int bid = blockIdx.x, tid = threadIdx.x;
    const int gtid = bid * TPB + tid;
    const int N = p.N, E = p.E;

    // ---- Phase A: zero cnt; W1T = bf16(W1^T); W2T = bf16(W2^T zero-padded to 48) ----
    for (int i = gtid; i < N; i += NTHR) p.cnt[i] = 0;
    for (int i = gtid; i < DIN * DH; i += NTHR) {
        int k = i / DH, n = i % DH;
        p.W1T[(size_t)n * DIN + k] = f2bf(p.W1[i]);
    }
    for (int i = gtid; i < 48 * DH; i += NTHR) {
        int n = i / DH, k = i % DH;
        p.W2T[i] = (n < DOUT) ? f2bf(p.W2[(size_t)k * DOUT + n]) : (ushort)0;
    }
    grid.sync();

    // ---- Phase B: degree histogram ----
    for (int e = gtid; e < E; e += NTHR) atomicAdd(&p.cnt[p.dst[e]], 1);
    grid.sync();

    // ---- Phase C: per-block sums (block bid covers cnt[bid*256 .. +255]) ----
    {
        int i = gtid;
        int c = (i < N) ? p.cnt[i] : 0;
        int s = c;
        #pragma unroll
        for (int off = 32; off >= 1; off >>= 1) s += __shfl_down(s, off, 64);
        if ((tid & 63) == 0) ldsI[tid >> 6] = s;
        __syncthreads();
        if (tid == 0) p.bsum[bid] = ldsI[0] + ldsI[1] + ldsI[2] + ldsI[3];
    }
    grid.sync();

    // ---- Phase D: block 0 scans 512 block sums -> boff (exclusive) ----
    if (bid == 0) {
        __syncthreads();
        int v0 = p.bsum[tid], v1 = p.bsum[tid + 256];
        ldsI[tid] = v0; ldsI[tid + 256] = v1;
        __syncthreads();
        for (int off = 1; off < 512; off <<= 1) {
            int a0 = (tid >= off) ? ldsI[tid - off] : 0;
            int a1 = (tid + 256 >= off) ? ldsI[tid + 256 - off] : 0;
            __syncthreads();
            ldsI[tid] += a0; ldsI[tid + 256] += a1;
            __syncthreads();
        }
        p.boff[tid] = ldsI[tid] - v0;
        p.boff[tid + 256] = ldsI[tid + 256] - v1;
    }
    grid.sync();

    // ---- Phase E: row_ptr / cursor / dinv via block-local scan ----
    {
        int i = gtid;
        int c = (i < N) ? p.cnt[i] : 0;
        ldsI[tid] = c;
        __syncthreads();
        for (int off = 1; off < 256; off <<= 1) {
            int a = (tid >= off) ? ldsI[tid - off] : 0;
            __syncthreads();
            ldsI[tid] += a;
            __syncthreads();
        }
        int excl = ldsI[tid] - c;
        if (i < N) {
            int base = p.boff[bid] + excl;
            p.row_ptr[i] = base;
            p.cursor[i]  = base;
            p.dinv[i] = rsqrtf(1.0f + (float)c);
            if (i == N - 1) p.row_ptr[N] = base + c;
        }
    }
    grid.sync();

    // ---- Phase F: CSR fill ----
    for (int e = gtid; e < E; e += NTHR) {
        int pos = atomicAdd(&p.cursor[p.dst[e]], 1);
        p.adj[pos] = p.src[e];
    }
    grid.sync();

    // ---- Phase G: GEMM1 (MFMA bf16): hs1 = bf16((x@W1)*dinv) ----
    {
        const int lane = tid & 63, w = tid >> 6;
        const int rb = (w >> 1) * 64, cb = (w & 1) * 48;
        const int lm = lane & 15, lq = lane >> 4;
        int aof[4][2], bof[3][2];
        #pragma unroll
        for (int i = 0; i < 4; ++i)
            #pragma unroll
            for (int ks = 0; ks < 2; ++ks) {
                int r = rb + i * 16 + lm, c = ks * 32 + lq * 8;
                aof[i][ks] = r * 64 + (c ^ ((r & 7) << 3));
            }
        #pragma unroll
        for (int j = 0; j < 3; ++j)
            #pragma unroll
            for (int ks = 0; ks < 2; ++ks) {
                int n = cb + j * 16 + lm, c = ks * 32 + lq * 8;
                bof[j][ks] = 16384 + n * 64 + (c ^ ((n & 7) << 3));
            }
        const int sr = tid >> 1, scb = (tid & 1) * 32;
        const int ntile = (N + 127) / 128;

        for (int t = bid; t < ntile; t += NBLK) {
            const int row0 = t * 128;
            f4v acc[4][3];
            #pragma unroll
            for (int i = 0; i < 4; ++i)
                #pragma unroll
                for (int j = 0; j < 3; ++j) acc[i][j] = (f4v)0.f;

            auto stage = [&](int kt, int buf) {
                int k0 = kt * 64;
                int gr = row0 + sr;
                ushort* A = lds + buf * 8192;
                #pragma unroll
                for (int s = 0; s < 4; ++s) {
                    int c = scb + s * 8;
                    float4 v0 = make_float4(0.f, 0.f, 0.f, 0.f), v1 = v0;
                    if (gr < N) {
                        const float* pp = &p.x[(size_t)gr * DIN + k0 + c];
                        v0 = *(const float4*)pp;
                        v1 = *(const float4*)(pp + 4);
                    }
                    uint4 wv;
                    wv.x = (uint)f2bf(v0.x) | ((uint)f2bf(v0.y) << 16);
                    wv.y = (uint)f2bf(v0.z) | ((uint)f2bf(v0.w) << 16);
                    wv.z = (uint)f2bf(v1.x) | ((uint)f2bf(v1.y) << 16);
                    wv.w = (uint)f2bf(v1.z) | ((uint)f2bf(v1.w) << 16);
                    *(uint4*)&A[sr * 64 + (c ^ ((sr & 7) << 3))] = wv;
                }
                ushort* B = lds + 16384 + buf * 6144;
                #pragma unroll
                for (int it = 0; it < 3; ++it) {
                    int ss = tid + it * 256;
                    int n = ss >> 3, c = (ss & 7) * 8;
                    uint4 wv = *(const uint4*)&p.W1T[(size_t)n * DIN + k0 + c];
                    *(uint4*)&B[n * 64 + (c ^ ((n & 7) << 3))] = wv;
                }
            };

            __syncthreads();          // protect LDS from previous tile's readers
            stage(0, 0);
            for (int kt = 0; kt < 8; ++kt) {
                __syncthreads();
                if (kt < 7) stage(kt + 1, (kt + 1) & 1);
                const int ab = (kt & 1) * 8192;
                const int bb = (kt & 1) * 6144;
                #pragma unroll
                for (int ks = 0; ks < 2; ++ks) {
                    s8v b0 = *(s8v*)&lds[bof[0][ks] + bb];
                    s8v b1 = *(s8v*)&lds[bof[1][ks] + bb];
                    s8v b2 = *(s8v*)&lds[bof[2][ks] + bb];
                    #pragma unroll
                    for (int i = 0; i < 4; ++i) {
                        s8v a = *(s8v*)&lds[aof[i][ks] + ab];
                        acc[i][0] = __builtin_amdgcn_mfma_f32_16x16x32_bf16(a, b0, acc[i][0], 0, 0, 0);
                        acc[i][1] = __builtin_amdgcn_mfma_f32_16x16x32_bf16(a, b1, acc[i][1], 0, 0, 0);
                        acc[i][2] = __builtin_amdgcn_mfma_f32_16x16x32_bf16(a, b2, acc[i][2], 0, 0, 0);
                    }
                }
            }
            #pragma unroll
            for (int i = 0; i < 4; ++i) {
                int gr0 = row0 + rb + i * 16 + lq * 4;
                #pragma unroll
                for (int q = 0; q < 4; ++q) {
                    int gr = gr0 + q;
                    if (gr < N) {
                        float di = p.dinv[gr];
                        #pragma unroll
                        for (int j = 0; j < 3; ++j)
                            p.hs1[(size_t)gr * DH + cb + j * 16 + lm] = f2bf(acc[i][j][q] * di);
                    }
                }
            }
        }
    }
    grid.sync();

    // ---- Phase H: agg1 (wave per node): h1 = bf16(relu(dinv*(self+sum)+b1)) ----
    {
        const int lane = tid & 63;
        const int wid = gtid >> 6;
        const int c = lane << 1;
        const bool act = (c < DH);
        for (int node = wid; node < N; node += NWAVE) {
            float a0 = 0.f, a1 = 0.f;
            if (act) {
                uint u = *(const uint*)&p.hs1[(size_t)node * DH + c];
                a0 = bflo(u); a1 = bfhi(u);
            }
            int e = p.row_ptr[node], e1 = p.row_ptr[node + 1];
            for (; e + 3 < e1; e += 4) {
                int s0 = p.adj[e], s1 = p.adj[e + 1], s2 = p.adj[e + 2], s3 = p.adj[e + 3];
                if (act) {
                    uint u0 = *(const uint*)&p.hs1[(size_t)s0 * DH + c];
                    uint u1 = *(const uint*)&p.hs1[(size_t)s1 * DH + c];
                    uint u2 = *(const uint*)&p.hs1[(size_t)s2 * DH + c];
                    uint u3 = *(const uint*)&p.hs1[(size_t)s3 * DH + c];
                    a0 += bflo(u0); a1 += bfhi(u0);
                    a0 += bflo(u1); a1 += bfhi(u1);
                    a0 += bflo(u2); a1 += bfhi(u2);
                    a0 += bflo(u3); a1 += bfhi(u3);
                }
            }
            for (; e < e1; ++e) {
                int s = p.adj[e];
                if (act) {
                    uint u = *(const uint*)&p.hs1[(size_t)s * DH + c];
                    a0 += bflo(u); a1 += bfhi(u);
                }
            }
            if (act) {
                float di = p.dinv[node];
                float r0 = fmaxf(fmaf(a0, di, p.b1[c]), 0.f);
                float r1 = fmaxf(fmaf(a1, di, p.b1[c + 1]), 0.f);
                *(uint*)&p.h1[(size_t)node * DH + c] = (uint)f2bf(r0) | ((uint)f2bf(r1) << 16);
            }
        }
    }
    grid.sync();

    // ---- Phase I: GEMM2 (MFMA bf16): hs2 = (h1@W2)*dinv (f32) ----
    {
        // stage W2T once: 48 x 96 -> lds[16384 + r*128 + swz]
        for (int f = tid; f < 576; f += 256) {
            int r = f / 12, c = (f % 12) * 8;
            uint4 v = *(const uint4*)&p.W2T[r * DH + c];
            *(uint4*)&lds[16384 + r * 128 + (c ^ ((r & 7) << 3))] = v;
        }
        const int lane = tid & 63, w = tid >> 6;
        const int rb = w * 32, lm = lane & 15, lq = lane >> 4;
        const int ntile = (N + 127) / 128;

        for (int t = bid; t < ntile; t += NBLK) {
            const int row0 = t * 128;
            __syncthreads();
            {
                int r = tid >> 1, half = tid & 1;
                int gr = row0 + r;
                #pragma unroll
                for (int i = 0; i < 6; ++i) {
                    int c = half * 48 + i * 8;
                    uint4 v = make_uint4(0, 0, 0, 0);
                    if (gr < N) v = *(const uint4*)&p.h1[(size_t)gr * DH + c];
                    *(uint4*)&lds[r * 128 + (c ^ ((r & 7) << 3))] = v;
                }
            }
            __syncthreads();

            f4v acc[2][3];
            #pragma unroll
            for (int i = 0; i < 2; ++i)
                #pragma unroll
                for (int j = 0; j < 3; ++j) acc[i][j] = (f4v)0.f;

            #pragma unroll
            for (int ks = 0; ks < 3; ++ks) {
                int kk = ks * 32 + lq * 8;
                s8v b[3];
                #pragma unroll
                for (int j = 0; j < 3; ++j) {
                    int n = j * 16 + lm;
                    b[j] = *(s8v*)&lds[16384 + n * 128 + (kk ^ ((n & 7) << 3))];
                }
                #pragma unroll
                for (int i = 0; i < 2; ++i) {
                    int r = rb + i * 16 + lm;
                    s8v a = *(s8v*)&lds[r * 128 + (kk ^ ((r & 7) << 3))];
                    #pragma unroll
                    for (int j = 0; j < 3; ++j)
                        acc[i][j] = __builtin_amdgcn_mfma_f32_16x16x32_bf16(a, b[j], acc[i][j], 0, 0, 0);
                }
            }
            #pragma unroll
            for (int i = 0; i < 2; ++i) {
                int gr0 = row0 + rb + i * 16 + lq * 4;
                #pragma unroll
                for (int q = 0; q < 4; ++q) {
                    int gr = gr0 + q;
                    if (gr < N) {
                        float di = p.dinv[gr];
                        #pragma unroll
                        for (int j = 0; j < 3; ++j) {
                            int col = j * 16 + lm;
                            if (col < DOUT)
                                p.hs2[(size_t)gr * DOUT + col] = acc[i][j][q] * di;
                        }
                    }
                }
            }
        }
    }
    grid.sync();

    // ---- Phase J: agg2 + bias + log_softmax (wave per node) ----
    {
        const int lane = tid & 63;
        const int wid = gtid >> 6;
        const bool act = lane < DOUT;
        for (int node = wid; node < N; node += NWAVE) {
            float acc = act ? p.hs2[(size_t)node * DOUT + lane] : 0.f;
            int e = p.row_ptr[node], e1 = p.row_ptr[node + 1];
            for (; e + 3 < e1; e += 4) {
                int s0 = p.adj[e], s1 = p.adj[e + 1], s2 = p.adj[e + 2], s3 = p.adj[e + 3];
                if (act) {
                    acc += p.hs2[(size_t)s0 * DOUT + lane] + p.hs2[(size_t)s1 * DOUT + lane]
                         + p.hs2[(size_t)s2 * DOUT + lane] + p.hs2[(size_t)s3 * DOUT + lane];
                }
            }
            for (; e < e1; ++e) {
                int s = p.adj[e];
                if (act) acc += p.hs2[(size_t)s * DOUT + lane];
            }
            float v = act ? fmaf(acc, p.dinv[node], p.b2[lane]) : -1e30f;
            float m = v;
            #pragma unroll
            for (int off = 32; off >= 1; off >>= 1) m = fmaxf(m, __shfl_xor(m, off));
            float ex = act ? __expf(v - m) : 0.f;
            float s = ex;
            #pragma unroll
            for (int off = 32; off >= 1; off >>= 1) s += __shfl_xor(s, off);
            float lse = m + __logf(s);
            if (act) {
                p.out[(size_t)node * DOUT + lane] = v;
                p.lsm[(size_t)node * DOUT + lane] = v - lse;
            }
        }
    }
}

// ===================== fallback multi-kernel path (R5) =====================
__global__ __launch_bounds__(256) void k_prep(
    const float* __restrict__ W1, const float* __restrict__ W2,
    int* __restrict__ cnt, ushort* __restrict__ W1T, ushort* __restrict__ W2T, int N)
{
    int i = blockIdx.x * 256 + threadIdx.x;
    if (i < N) cnt[i] = 0;
    if (i < DIN * DH) {
        int k = i / DH, n = i % DH;
        W1T[(size_t)n * DIN + k] = f2bf(W1[i]);
    }
    if (i < 48 * DH) {
        int n = i / DH, k = i % DH;
        W2T[i] = (n < DOUT) ? f2bf(W2[(size_t)k * DOUT + n]) : (ushort)0;
    }
}

__global__ __launch_bounds__(256) void k_hist(const int* __restrict__ dst, int* __restrict__ cnt, int E) {
    int e = blockIdx.x * 256 + threadIdx.x;
    if (e < E) atomicAdd(&cnt[dst[e]], 1);
}

__global__ __launch_bounds__(256) void k_blocksum(const int* __restrict__ cnt, int* __restrict__ bsum, int N) {
    int i = blockIdx.x * 256 + threadIdx.x;
    int c = (i < N) ? cnt[i] : 0;
    #pragma unroll
    for (int off = 32; off >= 1; off >>= 1) c += __shfl_down(c, off, 64);
    __shared__ int wsum[4];
    if ((threadIdx.x & 63) == 0) wsum[threadIdx.x >> 6] = c;
    __syncthreads();
    if (threadIdx.x == 0) bsum[blockIdx.x] = wsum[0] + wsum[1] + wsum[2] + wsum[3];
}

__global__ __launch_bounds__(256) void k_scan_small(const int* __restrict__ bsum, int* __restrict__ boff, int SB) {
    __shared__ int pp[256];
    int tid = threadIdx.x;
    int v = (tid < SB) ? bsum[tid] : 0;
    pp[tid] = v;
    __syncthreads();
    #pragma unroll
    for (int off = 1; off < 256; off <<= 1) {
        int t = (tid >= off) ? pp[tid - off] : 0;
        __syncthreads();
        pp[tid] += t;
        __syncthreads();
    }
    if (tid < SB) boff[tid] = pp[tid] - v;
}

__global__ __launch_bounds__(256) void k_rowptr(
    const int* __restrict__ cnt, const int* __restrict__ boff,
    int* __restrict__ row_ptr, int* __restrict__ cursor,
    float* __restrict__ dinv, int N)
{
    __shared__ int pp[256];
    int tid = threadIdx.x;
    int i = blockIdx.x * 256 + tid;
    int c = (i < N) ? cnt[i] : 0;
    pp[tid] = c;
    __syncthreads();
    #pragma unroll
    for (int off = 1; off < 256; off <<= 1) {
        int t = (tid >= off) ? pp[tid - off] : 0;
        __syncthreads();
        pp[tid] += t;
        __syncthreads();
    }
    int excl = pp[tid] - c;
    if (i < N) {
        int base = boff[blockIdx.x] + excl;
        row_ptr[i] = base;
        cursor[i]  = base;
        dinv[i] = rsqrtf(1.0f + (float)c);
        if (i == N - 1) row_ptr[N] = base + c;
    }
}

__global__ __launch_bounds__(256) void k_fill(
    const int* __restrict__ src, const int* __restrict__ dst,
    int* __restrict__ cursor, int* __restrict__ adj, int E)
{
    int e = blockIdx.x * 256 + threadIdx.x;
    if (e >= E) return;
    int pos = atomicAdd(&cursor[dst[e]], 1);
    adj[pos] = src[e];
}

__global__ __launch_bounds__(256) void k_gemm1s(
    const float* __restrict__ x, const ushort* __restrict__ W1T,
    const float* __restrict__ dinv, ushort* __restrict__ hs1, int N)
{
    __shared__ __align__(16) ushort lds[28672];
    const int tid = threadIdx.x;
    const int row0 = blockIdx.x * 128;
    const int lane = tid & 63, w = tid >> 6;
    const int rb = (w >> 1) * 64, cb = (w & 1) * 48;
    const int lm = lane & 15, lq = lane >> 4;

    int aof[4][2], bof[3][2];
    #pragma unroll
    for (int i = 0; i < 4; ++i)
        #pragma unroll
        for (int ks = 0; ks < 2; ++ks) {
            int r = rb + i * 16 + lm, c = ks * 32 + lq * 8;
            aof[i][ks] = r * 64 + (c ^ ((r & 7) << 3));
        }
    #pragma unroll
    for (int j = 0; j < 3; ++j)
        #pragma unroll
        for (int ks = 0; ks < 2; ++ks) {
            int n = cb + j * 16 + lm, c = ks * 32 + lq * 8;
            bof[j][ks] = 16384 + n * 64 + (c ^ ((n & 7) << 3));
        }

    f4v acc[4][3];
    #pragma unroll
    for (int i = 0; i < 4; ++i)
        #pragma unroll
        for (int j = 0; j < 3; ++j) acc[i][j] = (f4v)0.f;

    const int sr = tid >> 1, scb = (tid & 1) * 32;

    auto stage = [&](int kt, int buf) {
        int k0 = kt * 64;
        int gr = row0 + sr;
        ushort* A = lds + buf * 8192;
        #pragma unroll
        for (int s = 0; s < 4; ++s) {
            int c = scb + s * 8;
            float4 v0 = make_float4(0.f, 0.f, 0.f, 0.f), v1 = v0;
            if (gr < N) {
                const float* pp = &x[(size_t)gr * DIN + k0 + c];
                v0 = *(const float4*)pp;
                v1 = *(const float4*)(pp + 4);
            }
            uint4 wv;
            wv.x = (uint)f2bf(v0.x) | ((uint)f2bf(v0.y) << 16);
            wv.y = (uint)f2bf(v0.z) | ((uint)f2bf(v0.w) << 16);
            wv.z = (uint)f2bf(v1.x) | ((uint)f2bf(v1.y) << 16);
            wv.w = (uint)f2bf(v1.z) | ((uint)f2bf(v1.w) << 16);
            *(uint4*)&A[sr * 64 + (c ^ ((sr & 7) << 3))] = wv;
        }
        ushort* B = lds + 16384 + buf * 6144;
        #pragma unroll
        for (int it = 0; it < 3; ++it) {
            int ss = tid + it * 256;
            int n = ss >> 3, c = (ss & 7) * 8;
            uint4 wv = *(const uint4*)&W1T[(size_t)n * DIN + k0 + c];
            *(uint4*)&B[n * 64 + (c ^ ((n & 7) << 3))] = wv;
        }
    };

    stage(0, 0);
    for (int kt = 0; kt < 8; ++kt) {
        __syncthreads();
        if (kt < 7) stage(kt + 1, (kt + 1) & 1);
        const int ab = (kt & 1) * 8192;
        const int bb = (kt & 1) * 6144;
        #pragma unroll
        for (int ks = 0; ks < 2; ++ks) {
            s8v b0 = *(s8v*)&lds[bof[0][ks] + bb];
            s8v b1 = *(s8v*)&lds[bof[1][ks] + bb];
            s8v b2 = *(s8v*)&lds[bof[2][ks] + bb];
            #pragma unroll
            for (int i = 0; i < 4; ++i) {
                s8v a = *(s8v*)&lds[aof[i][ks] + ab];
                acc[i][0] = __builtin_amdgcn_mfma_f32_16x16x32_bf16(a, b0, acc[i][0], 0, 0, 0);
                acc[i][1] = __builtin_amdgcn_mfma_f32_16x16x32_bf16(a, b1, acc[i][1], 0, 0, 0);
                acc[i][2] = __builtin_amdgcn_mfma_f32_16x16x32_bf16(a, b2, acc[i][2], 0, 0, 0);
            }
        }
    }

    #pragma unroll
    for (int i = 0; i < 4; ++i) {
        int gr0 = row0 + rb + i * 16 + lq * 4;
        #pragma unroll
        for (int q = 0; q < 4; ++q) {
            int gr = gr0 + q;
            if (gr < N) {
                float di = dinv[gr];
                #pragma unroll
                for (int j = 0; j < 3; ++j)
                    hs1[(size_t)gr * DH + cb + j * 16 + lm] = f2bf(acc[i][j][q] * di);
            }
        }
    }
}

__global__ __launch_bounds__(256) void k_agg1(
    const int* __restrict__ row_ptr, const int* __restrict__ adj,
    const float* __restrict__ dinv, const ushort* __restrict__ hs1,
    const float* __restrict__ b1, ushort* __restrict__ h1, int N)
{
    int t = blockIdx.x * 256 + threadIdx.x;
    int node = t >> 6, lane = t & 63;
    if (node >= N) return;
    int c = lane << 1;
    const bool act = (c < DH);

    float a0 = 0.f, a1 = 0.f;
    if (act) {
        uint u = *(const uint*)&hs1[(size_t)node * DH + c];
        a0 = bflo(u); a1 = bfhi(u);
    }
    int e = row_ptr[node], e1 = row_ptr[node + 1];
    for (; e + 3 < e1; e += 4) {
        int s0 = adj[e], s1 = adj[e + 1], s2 = adj[e + 2], s3 = adj[e + 3];
        if (act) {
            uint u0 = *(const uint*)&hs1[(size_t)s0 * DH + c];
            uint u1 = *(const uint*)&hs1[(size_t)s1 * DH + c];
            uint u2 = *(const uint*)&hs1[(size_t)s2 * DH + c];
            uint u3 = *(const uint*)&hs1[(size_t)s3 * DH + c];
            a0 += bflo(u0); a1 += bfhi(u0);
            a0 += bflo(u1); a1 += bfhi(u1);
            a0 += bflo(u2); a1 += bfhi(u2);
            a0 += bflo(u3); a1 += bfhi(u3);
        }
    }
    for (; e < e1; ++e) {
        int s = adj[e];
        if (act) {
            uint u = *(const uint*)&hs1[(size_t)s * DH + c];
            a0 += bflo(u); a1 += bfhi(u);
        }
    }
    if (act) {
        float di = dinv[node];
        float r0 = fmaxf(fmaf(a0, di, b1[c]), 0.f);
        float r1 = fmaxf(fmaf(a1, di, b1[c + 1]), 0.f);
        *(uint*)&h1[(size_t)node * DH + c] = (uint)f2bf(r0) | ((uint)f2bf(r1) << 16);
    }
}

__global__ __launch_bounds__(256) void k_gemm2s(
    const ushort* __restrict__ h1, const ushort* __restrict__ W2T,
    const float* __restrict__ dinv, float* __restrict__ hs2, int N)
{
    __shared__ __align__(16) ushort lds[16384 + 48 * 128];
    const int tid = threadIdx.x;
    const int row0 = blockIdx.x * 128;

    for (int f = tid; f < 576; f += 256) {
        int r = f / 12, c = (f % 12) * 8;
        uint4 v = *(const uint4*)&W2T[r * DH + c];
        *(uint4*)&lds[16384 + r * 128 + (c ^ ((r & 7) << 3))] = v;
    }
    {
        int r = tid >> 1, half = tid & 1;
        int gr = row0 + r;
        #pragma unroll
        for (int i = 0; i < 6; ++i) {
            int c = half * 48 + i * 8;
            uint4 v = make_uint4(0, 0, 0, 0);
            if (gr < N) v = *(const uint4*)&h1[(size_t)gr * DH + c];
            *(uint4*)&lds[r * 128 + (c ^ ((r & 7) << 3))] = v;
        }
    }
    __syncthreads();

    const int lane = tid & 63, w = tid >> 6;
    const int rb = w * 32, lm = lane & 15, lq = lane >> 4;
    f4v acc[2][3];
    #pragma unroll
    for (int i = 0; i < 2; ++i)
        #pragma unroll
        for (int j = 0; j < 3; ++j) acc[i][j] = (f4v)0.f;

    #pragma unroll
    for (int ks = 0; ks < 3; ++ks) {
        int kk = ks * 32 + lq * 8;
        s8v b[3];
        #pragma unroll
        for (int j = 0; j < 3; ++j) {
            int n = j * 16 + lm;
            b[j] = *(s8v*)&lds[16384 + n * 128 + (kk ^ ((n & 7) << 3))];
        }
        #pragma unroll
        for (int i = 0; i < 2; ++i) {
            int r = rb + i * 16 + lm;
            s8v a = *(s8v*)&lds[r * 128 + (kk ^ ((r & 7) << 3))];
            #pragma unroll
            for (int j = 0; j < 3; ++j)
                acc[i][j] = __builtin_amdgcn_mfma_f32_16x16x32_bf16(a, b[j], acc[i][j], 0, 0, 0);
        }
    }

    #pragma unroll
    for (int i = 0; i < 2; ++i) {
        int gr0 = row0 + rb + i * 16 + lq * 4;
        #pragma unroll
        for (int q = 0; q < 4; ++q) {
            int gr = gr0 + q;
            if (gr < N) {
                float di = dinv[gr];
                #pragma unroll
                for (int j = 0; j < 3; ++j) {
                    int col = j * 16 + lm;
                    if (col < DOUT)
                        hs2[(size_t)gr * DOUT + col] = acc[i][j][q] * di;
                }
            }
        }
    }
}

__global__ __launch_bounds__(256) void k_agg2sm(
    const int* __restrict__ row_ptr, const int* __restrict__ adj,
    const float* __restrict__ dinv, const float* __restrict__ hs2,
    const float* __restrict__ b2, float* __restrict__ out,
    float* __restrict__ lsm, int N)
{
    int t = blockIdx.x * 256 + threadIdx.x;
    int node = t >> 6, lane = t & 63;
    if (node >= N) return;
    const bool act = lane < DOUT;

    float acc = act ? hs2[(size_t)node * DOUT + lane] : 0.f;
    int e = row_ptr[node], e1 = row_ptr[node + 1];
    for (; e + 3 < e1; e += 4) {
        int s0 = adj[e], s1 = adj[e + 1], s2 = adj[e + 2], s3 = adj[e + 3];
        if (act) {
            acc += hs2[(size_t)s0 * DOUT + lane] + hs2[(size_t)s1 * DOUT + lane]
                 + hs2[(size_t)s2 * DOUT + lane] + hs2[(size_t)s3 * DOUT + lane];
        }
    }
    for (; e < e1; ++e) {
        int s = adj[e];
        if (act) acc += hs2[(size_t)s * DOUT + lane];
    }

    float v = act ? fmaf(acc, dinv[node], b2[lane]) : -1e30f;
    float m = v;
    #pragma unroll
    for (int off = 32; off >= 1; off >>= 1) m = fmaxf(m, __shfl_xor(m, off));
    float ex = act ? __expf(v - m) : 0.f;
    float s = ex;
    #pragma unroll
    for (int off = 32; off >= 1; off >>= 1) s += __shfl_xor(s, off);
    float lse = m + __logf(s);
    if (act) {
        out[(size_t)node * DOUT + lane] = v;
        lsm[(size_t)node * DOUT + lane] = v - lse;
    }
}

extern "C" void kernel_launch(void* const* d_in, const int* in_sizes, int n_in,
                              void* d_out, int out_size, void* d_ws, size_t ws_size,
                              hipStream_t stream) {
    const float* x  = (const float*)d_in[0];
    const int*   ei = (const int*)d_in[1];
    const float* W1 = (const float*)d_in[2];
    const float* b1 = (const float*)d_in[3];
    const float* W2 = (const float*)d_in[4];
    const float* b2 = (const float*)d_in[5];

    const int N = in_sizes[0] / DIN;
    const int E = in_sizes[1] / 2;
    const int* srcp = ei;
    const int* dstp = ei + E;

    ushort* hs1 = (ushort*)d_ws;                    // N*96 bf16
    ushort* h1  = hs1 + (size_t)N * DH;             // N*96 bf16
    float* hs2  = (float*)(h1 + (size_t)N * DH);    // N*40 f32
    float* dinv = hs2 + (size_t)N * DOUT;           // N
    ushort* W1T = (ushort*)(dinv + N);              // 96*512 bf16
    ushort* W2T = W1T + (size_t)DH * DIN;           // 48*96 bf16
    int* cnt     = (int*)(W2T + 48 * DH);           // N
    int* cursor  = cnt + N;                         // N
    int* row_ptr = cursor + N;                      // N+1
    int* adj     = row_ptr + N + 1;                 // E
    int* bsum    = adj + E;                         // NBLK
    int* boff    = bsum + NBLK;                     // NBLK

    float* out = (float*)d_out;
    float* lsm = out + (size_t)N * DOUT;

    Params prm;
    prm.x = x; prm.src = srcp; prm.dst = dstp;
    prm.W1 = W1; prm.b1 = b1; prm.W2 = W2; prm.b2 = b2;
    prm.hs1 = hs1; prm.h1 = h1; prm.hs2 = hs2; prm.dinv = dinv;
    prm.W1T = W1T; prm.W2T = W2T;
    prm.cnt = cnt; prm.cursor = cursor; prm.row_ptr = row_ptr; prm.adj = adj;
    prm.bsum = bsum; prm.boff = boff;
    prm.out = out; prm.lsm = lsm;
    prm.N = N; prm.E = E;

    void* args[] = { &prm };
    hipError_t err = hipLaunchCooperativeKernel((const void*)k_mega, dim3(NBLK), dim3(TPB),
                                                args, 0, stream);
    if (err == hipSuccess) return;

    // -------- fallback: multi-kernel path --------
    const int SB = (N + 255) / 256;
    const int gE = (E + 255) / 256;
    k_prep<<<SB, 256, 0, stream>>>(W1, W2, cnt, W1T, W2T, N);
    k_hist<<<gE, 256, 0, stream>>>(dstp, cnt, E);
    k_blocksum<<<SB, 256, 0, stream>>>(cnt, bsum, N);
    k_scan_small<<<1, 256, 0, stream>>>(bsum, boff, SB);
    k_rowptr<<<SB, 256, 0, stream>>>(cnt, boff, row_ptr, cursor, dinv, N);
    k_fill<<<gE, 256, 0, stream>>>(srcp, dstp, cursor, adj, E);
    k_gemm1s<<<(N + 127) / 128, 256, 0, stream>>>(x, W1T, dinv, hs1, N);
    k_agg1<<<(int)(((size_t)N * 64 + 255) / 256), 256, 0, stream>>>(row_ptr, adj, dinv, hs1, b1, h1, N);
    k_gemm2s<<<(N + 127) / 128, 256, 0, stream>>>(h1, W2T, dinv, hs2, N);
    k_agg2sm<<<(int)(((size_t)N * 64 + 255) / 256), 256, 0, stream>>>(row_ptr, adj, dinv, hs2, b2, out, lsm, N);
}

// Round 7
// 185.189 us; speedup vs baseline: 4.7432x; 4.7432x over previous
//
#include <hip/hip_runtime.h>
#include <hip/hip_bf16.h>
#include <cstdint>
#include <cstddef>

#define DIN 512
#define DH  96
#define DOUT 40

typedef __attribute__((ext_vector_type(8))) short s8v;
typedef __attribute__((ext_vector_type(4))) float f4v;

__device__ __forceinline__ ushort f2bf(float f) {
    uint u = __float_as_uint(f);
    u += 0x7fffu + ((u >> 16) & 1u);   // RNE
    return (ushort)(u >> 16);
}
__device__ __forceinline__ uint f2bf2(float lo, float hi) {
    __hip_bfloat162 h = __float22bfloat162_rn(make_float2(lo, hi));  // v_cvt_pk_bf16_f32
    return *(uint*)&h;
}
__device__ __forceinline__ float bflo(uint u) { return __uint_as_float(u << 16); }
__device__ __forceinline__ float bfhi(uint u) { return __uint_as_float(u & 0xffff0000u); }

// ---------- prep: zero cnt + W1T bf16 [96][512] + W2T bf16 [48][96] ----------
__global__ __launch_bounds__(256) void k_prep(
    const float* __restrict__ W1, const float* __restrict__ W2,
    int* __restrict__ cnt, ushort* __restrict__ W1T, ushort* __restrict__ W2T, int N)
{
    int i = blockIdx.x * 256 + threadIdx.x;
    if (i < N) cnt[i] = 0;
    if (i < DIN * DH) {
        int k = i / DH, n = i % DH;
        W1T[(size_t)n * DIN + k] = f2bf(W1[i]);
    }
    if (i < 48 * DH) {
        int n = i / DH, k = i % DH;
        W2T[i] = (n < DOUT) ? f2bf(W2[(size_t)k * DOUT + n]) : (ushort)0;
    }
}

// ---------- hist + per-edge slot ----------
__global__ __launch_bounds__(256) void k_hist(
    const int* __restrict__ dst, int* __restrict__ cnt, int* __restrict__ pos, int E)
{
    int e = blockIdx.x * 256 + threadIdx.x;
    if (e < E) pos[e] = atomicAdd(&cnt[dst[e]], 1);
}

__global__ __launch_bounds__(256) void k_blocksum(const int* __restrict__ cnt, int* __restrict__ bsum, int N) {
    int i = blockIdx.x * 256 + threadIdx.x;
    int c = (i < N) ? cnt[i] : 0;
    #pragma unroll
    for (int off = 32; off >= 1; off >>= 1) c += __shfl_down(c, off, 64);
    __shared__ int wsum[4];
    if ((threadIdx.x & 63) == 0) wsum[threadIdx.x >> 6] = c;
    __syncthreads();
    if (threadIdx.x == 0) bsum[blockIdx.x] = wsum[0] + wsum[1] + wsum[2] + wsum[3];
}

__global__ __launch_bounds__(256) void k_scan_small(const int* __restrict__ bsum, int* __restrict__ boff, int SB) {
    __shared__ int p[256];
    int tid = threadIdx.x;
    int v = (tid < SB) ? bsum[tid] : 0;
    p[tid] = v;
    __syncthreads();
    #pragma unroll
    for (int off = 1; off < 256; off <<= 1) {
        int t = (tid >= off) ? p[tid - off] : 0;
        __syncthreads();
        p[tid] += t;
        __syncthreads();
    }
    if (tid < SB) boff[tid] = p[tid] - v;   // exclusive
}

__global__ __launch_bounds__(256) void k_rowptr(
    const int* __restrict__ cnt, const int* __restrict__ boff,
    int* __restrict__ row_ptr, float* __restrict__ dinv, int N)
{
    __shared__ int p[256];
    int tid = threadIdx.x;
    int i = blockIdx.x * 256 + tid;
    int c = (i < N) ? cnt[i] : 0;
    p[tid] = c;
    __syncthreads();
    #pragma unroll
    for (int off = 1; off < 256; off <<= 1) {
        int t = (tid >= off) ? p[tid - off] : 0;
        __syncthreads();
        p[tid] += t;
        __syncthreads();
    }
    int excl = p[tid] - c;
    if (i < N) {
        int base = boff[blockIdx.x] + excl;
        row_ptr[i] = base;
        dinv[i] = rsqrtf(1.0f + (float)c);
        if (i == N - 1) row_ptr[N] = base + c;
    }
}

// ---------- CSR fill (atomic-free: uses precomputed slots) ----------
__global__ __launch_bounds__(256) void k_fill(
    const int* __restrict__ src, const int* __restrict__ dst,
    const int* __restrict__ row_ptr, const int* __restrict__ pos,
    int* __restrict__ adj, int E)
{
    int e = blockIdx.x * 256 + threadIdx.x;
    if (e >= E) return;
    adj[row_ptr[dst[e]] + pos[e]] = src[e];
}

// ---------- GEMM1 (MFMA bf16): hs1 = bf16((x @ W1) * dinv) ----------
__global__ __launch_bounds__(256) void k_gemm1(
    const float* __restrict__ x, const ushort* __restrict__ W1T,
    const float* __restrict__ dinv, ushort* __restrict__ hs1, int N)
{
    __shared__ __align__(16) ushort lds[28672];   // 2*8192 A + 2*6144 B
    const int tid = threadIdx.x;
    const int row0 = blockIdx.x * 128;
    const int lane = tid & 63, w = tid >> 6;
    const int rb = (w >> 1) * 64, cb = (w & 1) * 48;
    const int lm = lane & 15, lq = lane >> 4;

    int aof[4][2], bof[3][2];
    #pragma unroll
    for (int i = 0; i < 4; ++i)
        #pragma unroll
        for (int ks = 0; ks < 2; ++ks) {
            int r = rb + i * 16 + lm, c = ks * 32 + lq * 8;
            aof[i][ks] = r * 64 + (c ^ ((r & 7) << 3));
        }
    #pragma unroll
    for (int j = 0; j < 3; ++j)
        #pragma unroll
        for (int ks = 0; ks < 2; ++ks) {
            int n = cb + j * 16 + lm, c = ks * 32 + lq * 8;
            bof[j][ks] = 16384 + n * 64 + (c ^ ((n & 7) << 3));
        }

    f4v acc[4][3];
    #pragma unroll
    for (int i = 0; i < 4; ++i)
        #pragma unroll
        for (int j = 0; j < 3; ++j) acc[i][j] = (f4v)0.f;

    const int sr = tid >> 1, scb = (tid & 1) * 32;

    auto stage = [&](int kt, int buf) {
        int k0 = kt * 64;
        int gr = row0 + sr;
        ushort* A = lds + buf * 8192;
        #pragma unroll
        for (int s = 0; s < 4; ++s) {
            int c = scb + s * 8;
            float4 v0 = make_float4(0.f, 0.f, 0.f, 0.f), v1 = v0;
            if (gr < N) {
                const float* pp = &x[(size_t)gr * DIN + k0 + c];
                v0 = *(const float4*)pp;
                v1 = *(const float4*)(pp + 4);
            }
            uint4 wv;
            wv.x = f2bf2(v0.x, v0.y);
            wv.y = f2bf2(v0.z, v0.w);
            wv.z = f2bf2(v1.x, v1.y);
            wv.w = f2bf2(v1.z, v1.w);
            *(uint4*)&A[sr * 64 + (c ^ ((sr & 7) << 3))] = wv;
        }
        ushort* B = lds + 16384 + buf * 6144;
        #pragma unroll
        for (int it = 0; it < 3; ++it) {
            int ss = tid + it * 256;
            int n = ss >> 3, c = (ss & 7) * 8;
            uint4 wv = *(const uint4*)&W1T[(size_t)n * DIN + k0 + c];
            *(uint4*)&B[n * 64 + (c ^ ((n & 7) << 3))] = wv;
        }
    };

    stage(0, 0);
    for (int kt = 0; kt < 8; ++kt) {
        __syncthreads();
        if (kt < 7) stage(kt + 1, (kt + 1) & 1);
        const int ab = (kt & 1) * 8192;
        const int bb = (kt & 1) * 6144;
        #pragma unroll
        for (int ks = 0; ks < 2; ++ks) {
            s8v b0 = *(s8v*)&lds[bof[0][ks] + bb];
            s8v b1 = *(s8v*)&lds[bof[1][ks] + bb];
            s8v b2 = *(s8v*)&lds[bof[2][ks] + bb];
            #pragma unroll
            for (int i = 0; i < 4; ++i) {
                s8v a = *(s8v*)&lds[aof[i][ks] + ab];
                acc[i][0] = __builtin_amdgcn_mfma_f32_16x16x32_bf16(a, b0, acc[i][0], 0, 0, 0);
                acc[i][1] = __builtin_amdgcn_mfma_f32_16x16x32_bf16(a, b1, acc[i][1], 0, 0, 0);
                acc[i][2] = __builtin_amdgcn_mfma_f32_16x16x32_bf16(a, b2, acc[i][2], 0, 0, 0);
            }
        }
    }

    #pragma unroll
    for (int i = 0; i < 4; ++i) {
        int gr0 = row0 + rb + i * 16 + lq * 4;
        #pragma unroll
        for (int q = 0; q < 4; ++q) {
            int gr = gr0 + q;
            if (gr < N) {
                float di = dinv[gr];
                #pragma unroll
                for (int j = 0; j < 3; ++j)
                    hs1[(size_t)gr * DH + cb + j * 16 + lm] = f2bf(acc[i][j][q] * di);
            }
        }
    }
}

// ---------- agg1: wave per node, 8-deep gather pipeline ----------
__global__ __launch_bounds__(256) void k_agg1(
    const int* __restrict__ row_ptr, const int* __restrict__ adj,
    const float* __restrict__ dinv, const ushort* __restrict__ hs1,
    const float* __restrict__ b1, ushort* __restrict__ h1, int N)
{
    int t = blockIdx.x * 256 + threadIdx.x;
    int node = t >> 6, lane = t & 63;
    if (node >= N) return;
    int c = lane << 1;
    const bool act = (c < DH);

    float a0 = 0.f, a1 = 0.f;
    if (act) {
        uint u = *(const uint*)&hs1[(size_t)node * DH + c];   // self-loop
        a0 = bflo(u); a1 = bfhi(u);
    }
    int e = row_ptr[node], e1 = row_ptr[node + 1];
    for (; e + 7 < e1; e += 8) {
        int s0 = adj[e],     s1 = adj[e + 1], s2 = adj[e + 2], s3 = adj[e + 3];
        int s4 = adj[e + 4], s5 = adj[e + 5], s6 = adj[e + 6], s7 = adj[e + 7];
        if (act) {
            uint u0 = *(const uint*)&hs1[(size_t)s0 * DH + c];
            uint u1 = *(const uint*)&hs1[(size_t)s1 * DH + c];
            uint u2 = *(const uint*)&hs1[(size_t)s2 * DH + c];
            uint u3 = *(const uint*)&hs1[(size_t)s3 * DH + c];
            uint u4 = *(const uint*)&hs1[(size_t)s4 * DH + c];
            uint u5 = *(const uint*)&hs1[(size_t)s5 * DH + c];
            uint u6 = *(const uint*)&hs1[(size_t)s6 * DH + c];
            uint u7 = *(const uint*)&hs1[(size_t)s7 * DH + c];
            a0 += bflo(u0); a1 += bfhi(u0);
            a0 += bflo(u1); a1 += bfhi(u1);
            a0 += bflo(u2); a1 += bfhi(u2);
            a0 += bflo(u3); a1 += bfhi(u3);
            a0 += bflo(u4); a1 += bfhi(u4);
            a0 += bflo(u5); a1 += bfhi(u5);
            a0 += bflo(u6); a1 += bfhi(u6);
            a0 += bflo(u7); a1 += bfhi(u7);
        }
    }
    for (; e < e1; ++e) {
        int s = adj[e];
        if (act) {
            uint u = *(const uint*)&hs1[(size_t)s * DH + c];
            a0 += bflo(u); a1 += bfhi(u);
        }
    }
    if (act) {
        float di = dinv[node];
        float r0 = fmaxf(fmaf(a0, di, b1[c]), 0.f);
        float r1 = fmaxf(fmaf(a1, di, b1[c + 1]), 0.f);
        *(uint*)&h1[(size_t)node * DH + c] = f2bf2(r0, r1);
    }
}

// ---------- GEMM2 (MFMA bf16): hs2 = (h1 @ W2) * dinv, f32 out ----------
__global__ __launch_bounds__(256) void k_gemm2(
    const ushort* __restrict__ h1, const ushort* __restrict__ W2T,
    const float* __restrict__ dinv, float* __restrict__ hs2, int N)
{
    __shared__ __align__(16) ushort lds[16384 + 48 * 128];
    const int tid = threadIdx.x;
    const int row0 = blockIdx.x * 128;

    for (int f = tid; f < 576; f += 256) {
        int r = f / 12, c = (f % 12) * 8;
        uint4 v = *(const uint4*)&W2T[r * DH + c];
        *(uint4*)&lds[16384 + r * 128 + (c ^ ((r & 7) << 3))] = v;
    }
    {
        int r = tid >> 1, half = tid & 1;
        int gr = row0 + r;
        #pragma unroll
        for (int i = 0; i < 6; ++i) {
            int c = half * 48 + i * 8;
            uint4 v = make_uint4(0, 0, 0, 0);
            if (gr < N) v = *(const uint4*)&h1[(size_t)gr * DH + c];
            *(uint4*)&lds[r * 128 + (c ^ ((r & 7) << 3))] = v;
        }
    }
    __syncthreads();

    const int lane = tid & 63, w = tid >> 6;
    const int rb = w * 32, lm = lane & 15, lq = lane >> 4;
    f4v acc[2][3];
    #pragma unroll
    for (int i = 0; i < 2; ++i)
        #pragma unroll
        for (int j = 0; j < 3; ++j) acc[i][j] = (f4v)0.f;

    #pragma unroll
    for (int ks = 0; ks < 3; ++ks) {
        int kk = ks * 32 + lq * 8;
        s8v b[3];
        #pragma unroll
        for (int j = 0; j < 3; ++j) {
            int n = j * 16 + lm;
            b[j] = *(s8v*)&lds[16384 + n * 128 + (kk ^ ((n & 7) << 3))];
        }
        #pragma unroll
        for (int i = 0; i < 2; ++i) {
            int r = rb + i * 16 + lm;
            s8v a = *(s8v*)&lds[r * 128 + (kk ^ ((r & 7) << 3))];
            #pragma unroll
            for (int j = 0; j < 3; ++j)
                acc[i][j] = __builtin_amdgcn_mfma_f32_16x16x32_bf16(a, b[j], acc[i][j], 0, 0, 0);
        }
    }

    #pragma unroll
    for (int i = 0; i < 2; ++i) {
        int gr0 = row0 + rb + i * 16 + lq * 4;
        #pragma unroll
        for (int q = 0; q < 4; ++q) {
            int gr = gr0 + q;
            if (gr < N) {
                float di = dinv[gr];
                #pragma unroll
                for (int j = 0; j < 3; ++j) {
                    int col = j * 16 + lm;
                    if (col < DOUT)
                        hs2[(size_t)gr * DOUT + col] = acc[i][j][q] * di;
                }
            }
        }
    }
}

// ---------- agg2 + bias + log_softmax fused: wave per node, 8-deep ----------
__global__ __launch_bounds__(256) void k_agg2sm(
    const int* __restrict__ row_ptr, const int* __restrict__ adj,
    const float* __restrict__ dinv, const float* __restrict__ hs2,
    const float* __restrict__ b2, float* __restrict__ out,
    float* __restrict__ lsm, int N)
{
    int t = blockIdx.x * 256 + threadIdx.x;
    int node = t >> 6, lane = t & 63;
    if (node >= N) return;
    const bool act = lane < DOUT;

    float acc = act ? hs2[(size_t)node * DOUT + lane] : 0.f;   // self-loop
    int e = row_ptr[node], e1 = row_ptr[node + 1];
    for (; e + 7 < e1; e += 8) {
        int s0 = adj[e],     s1 = adj[e + 1], s2 = adj[e + 2], s3 = adj[e + 3];
        int s4 = adj[e + 4], s5 = adj[e + 5], s6 = adj[e + 6], s7 = adj[e + 7];
        if (act) {
            float v0 = hs2[(size_t)s0 * DOUT + lane];
            float v1 = hs2[(size_t)s1 * DOUT + lane];
            float v2 = hs2[(size_t)s2 * DOUT + lane];
            float v3 = hs2[(size_t)s3 * DOUT + lane];
            float v4 = hs2[(size_t)s4 * DOUT + lane];
            float v5 = hs2[(size_t)s5 * DOUT + lane];
            float v6 = hs2[(size_t)s6 * DOUT + lane];
            float v7 = hs2[(size_t)s7 * DOUT + lane];
            acc += ((v0 + v1) + (v2 + v3)) + ((v4 + v5) + (v6 + v7));
        }
    }
    for (; e < e1; ++e) {
        int s = adj[e];
        if (act) acc += hs2[(size_t)s * DOUT + lane];
    }

    float v = act ? fmaf(acc, dinv[node], b2[lane]) : -1e30f;
    float m = v;
    #pragma unroll
    for (int off = 32; off >= 1; off >>= 1) m = fmaxf(m, __shfl_xor(m, off));
    float ex = act ? __expf(v - m) : 0.f;
    float s = ex;
    #pragma unroll
    for (int off = 32; off >= 1; off >>= 1) s += __shfl_xor(s, off);
    float lse = m + __logf(s);
    if (act) {
        out[(size_t)node * DOUT + lane] = v;
        lsm[(size_t)node * DOUT + lane] = v - lse;
    }
}

extern "C" void kernel_launch(void* const* d_in, const int* in_sizes, int n_in,
                              void* d_out, int out_size, void* d_ws, size_t ws_size,
                              hipStream_t stream) {
    const float* x  = (const float*)d_in[0];
    const int*   ei = (const int*)d_in[1];
    const float* W1 = (const float*)d_in[2];
    const float* b1 = (const float*)d_in[3];
    const float* W2 = (const float*)d_in[4];
    const float* b2 = (const float*)d_in[5];

    const int N = in_sizes[0] / DIN;
    const int E = in_sizes[1] / 2;
    const int* srcp = ei;
    const int* dstp = ei + E;
    const int SB = (N + 255) / 256;

    ushort* hs1 = (ushort*)d_ws;                    // N*96 bf16
    ushort* h1  = hs1 + (size_t)N * DH;             // N*96 bf16
    float* hs2  = (float*)(h1 + (size_t)N * DH);    // N*40 f32
    float* dinv = hs2 + (size_t)N * DOUT;           // N
    ushort* W1T = (ushort*)(dinv + N);              // 96*512 bf16
    ushort* W2T = W1T + (size_t)DH * DIN;           // 48*96 bf16
    int* cnt     = (int*)(W2T + 48 * DH);           // N
    int* row_ptr = cnt + N;                         // N+1
    int* adj     = row_ptr + N + 1;                 // E
    int* pos     = adj + E;                         // E
    int* bsum    = pos + E;                         // SB
    int* boff    = bsum + SB;                       // SB

    float* out = (float*)d_out;                     // logits [N*40]
    float* lsm = out + (size_t)N * DOUT;            // log_softmax [N*40]

    const int gE = (E + 255) / 256;

    k_prep<<<SB, 256, 0, stream>>>(W1, W2, cnt, W1T, W2T, N);
    k_hist<<<gE, 256, 0, stream>>>(dstp, cnt, pos, E);
    k_blocksum<<<SB, 256, 0, stream>>>(cnt, bsum, N);
    k_scan_small<<<1, 256, 0, stream>>>(bsum, boff, SB);
    k_rowptr<<<SB, 256, 0, stream>>>(cnt, boff, row_ptr, dinv, N);
    k_fill<<<gE, 256, 0, stream>>>(srcp, dstp, row_ptr, pos, adj, E);

    k_gemm1<<<(N + 127) / 128, 256, 0, stream>>>(x, W1T, dinv, hs1, N);
    k_agg1<<<(int)(((size_t)N * 64 + 255) / 256), 256, 0, stream>>>(row_ptr, adj, dinv, hs1, b1, h1, N);

    k_gemm2<<<(N + 127) / 128, 256, 0, stream>>>(h1, W2T, dinv, hs2, N);
    k_agg2sm<<<(int)(((size_t)N * 64 + 255) / 256), 256, 0, stream>>>(row_ptr, adj, dinv, hs2, b2, out, lsm, N);
}

// Round 8
// 181.287 us; speedup vs baseline: 4.8452x; 1.0215x over previous
//
#include <hip/hip_runtime.h>
#include <hip/hip_bf16.h>
#include <cstdint>
#include <cstddef>

#define DIN 512
#define DH  96
#define DOUT 40

typedef __attribute__((ext_vector_type(8))) short s8v;
typedef __attribute__((ext_vector_type(4))) float f4v;

__device__ __forceinline__ ushort f2bf(float f) {
    uint u = __float_as_uint(f);
    u += 0x7fffu + ((u >> 16) & 1u);   // RNE
    return (ushort)(u >> 16);
}
__device__ __forceinline__ uint f2bf2(float lo, float hi) {
    __hip_bfloat162 h = __float22bfloat162_rn(make_float2(lo, hi));  // v_cvt_pk_bf16_f32
    return *(uint*)&h;
}
__device__ __forceinline__ float bflo(uint u) { return __uint_as_float(u << 16); }
__device__ __forceinline__ float bfhi(uint u) { return __uint_as_float(u & 0xffff0000u); }

// ---------- prep: zero cnt + W1T bf16 [96][512] + W2T bf16 [48][96] ----------
__global__ __launch_bounds__(256) void k_prep(
    const float* __restrict__ W1, const float* __restrict__ W2,
    int* __restrict__ cnt, ushort* __restrict__ W1T, ushort* __restrict__ W2T, int N)
{
    int i = blockIdx.x * 256 + threadIdx.x;
    if (i < N) cnt[i] = 0;
    if (i < DIN * DH) {
        int k = i / DH, n = i % DH;
        W1T[(size_t)n * DIN + k] = f2bf(W1[i]);
    }
    if (i < 48 * DH) {
        int n = i / DH, k = i % DH;
        W2T[i] = (n < DOUT) ? f2bf(W2[(size_t)k * DOUT + n]) : (ushort)0;
    }
}

// ---------- hist + per-edge slot ----------
__global__ __launch_bounds__(256) void k_hist(
    const int* __restrict__ dst, int* __restrict__ cnt, int* __restrict__ pos, int E)
{
    int e = blockIdx.x * 256 + threadIdx.x;
    if (e < E) pos[e] = atomicAdd(&cnt[dst[e]], 1);
}

__global__ __launch_bounds__(256) void k_blocksum(const int* __restrict__ cnt, int* __restrict__ bsum, int N) {
    int i = blockIdx.x * 256 + threadIdx.x;
    int c = (i < N) ? cnt[i] : 0;
    #pragma unroll
    for (int off = 32; off >= 1; off >>= 1) c += __shfl_down(c, off, 64);
    __shared__ int wsum[4];
    if ((threadIdx.x & 63) == 0) wsum[threadIdx.x >> 6] = c;
    __syncthreads();
    if (threadIdx.x == 0) bsum[blockIdx.x] = wsum[0] + wsum[1] + wsum[2] + wsum[3];
}

__global__ __launch_bounds__(256) void k_scan_small(const int* __restrict__ bsum, int* __restrict__ boff, int SB) {
    __shared__ int p[256];
    int tid = threadIdx.x;
    int v = (tid < SB) ? bsum[tid] : 0;
    p[tid] = v;
    __syncthreads();
    #pragma unroll
    for (int off = 1; off < 256; off <<= 1) {
        int t = (tid >= off) ? p[tid - off] : 0;
        __syncthreads();
        p[tid] += t;
        __syncthreads();
    }
    if (tid < SB) boff[tid] = p[tid] - v;   // exclusive
}

__global__ __launch_bounds__(256) void k_rowptr(
    const int* __restrict__ cnt, const int* __restrict__ boff,
    int* __restrict__ row_ptr, float* __restrict__ dinv, int N)
{
    __shared__ int p[256];
    int tid = threadIdx.x;
    int i = blockIdx.x * 256 + tid;
    int c = (i < N) ? cnt[i] : 0;
    p[tid] = c;
    __syncthreads();
    #pragma unroll
    for (int off = 1; off < 256; off <<= 1) {
        int t = (tid >= off) ? p[tid - off] : 0;
        __syncthreads();
        p[tid] += t;
        __syncthreads();
    }
    int excl = p[tid] - c;
    if (i < N) {
        int base = boff[blockIdx.x] + excl;
        row_ptr[i] = base;
        dinv[i] = rsqrtf(1.0f + (float)c);
        if (i == N - 1) row_ptr[N] = base + c;
    }
}

// ---------- CSR fill (atomic-free) ----------
__global__ __launch_bounds__(256) void k_fill(
    const int* __restrict__ src, const int* __restrict__ dst,
    const int* __restrict__ row_ptr, const int* __restrict__ pos,
    int* __restrict__ adj, int E)
{
    int e = blockIdx.x * 256 + threadIdx.x;
    if (e >= E) return;
    adj[row_ptr[dst[e]] + pos[e]] = src[e];
}

// ---------- GEMM1 (MFMA bf16, BK=32, 28.7KB LDS -> 5 blocks/CU) ----------
// hs1 = bf16((x @ W1) * dinv); block tile 128x96, wave tile 64x48
#define SWZ(r) (((r >> 1) & 3) << 3)
__global__ __launch_bounds__(256) void k_gemm1(
    const float* __restrict__ x, const ushort* __restrict__ W1T,
    const float* __restrict__ dinv, ushort* __restrict__ hs1, int N)
{
    __shared__ __align__(16) ushort lds[14336];   // A: 2*4096, B: 2*3072
    const int tid = threadIdx.x;
    const int row0 = blockIdx.x * 128;
    const int lane = tid & 63, w = tid >> 6;
    const int rb = (w >> 1) * 64, cb = (w & 1) * 48;
    const int lm = lane & 15, lq = lane >> 4;

    int aof[4], bof[3];
    #pragma unroll
    for (int i = 0; i < 4; ++i) {
        int r = rb + i * 16 + lm;
        aof[i] = r * 32 + ((lq * 8) ^ SWZ(r));
    }
    #pragma unroll
    for (int j = 0; j < 3; ++j) {
        int n = cb + j * 16 + lm;
        bof[j] = 8192 + n * 32 + ((lq * 8) ^ SWZ(n));
    }

    f4v acc[4][3];
    #pragma unroll
    for (int i = 0; i < 4; ++i)
        #pragma unroll
        for (int j = 0; j < 3; ++j) acc[i][j] = (f4v)0.f;

    const int sr = tid >> 1;            // staging row
    const int c0 = (tid & 1) * 16;      // staging col base (16 cols per thread)

    auto stage = [&](int kt, int buf) {
        int k0 = kt * 32;
        int gr = row0 + sr;
        ushort* A = lds + buf * 4096;
        #pragma unroll
        for (int s = 0; s < 2; ++s) {
            int c = c0 + s * 8;
            float4 v0 = make_float4(0.f, 0.f, 0.f, 0.f), v1 = v0;
            if (gr < N) {
                const float* pp = &x[(size_t)gr * DIN + k0 + c];
                v0 = *(const float4*)pp;
                v1 = *(const float4*)(pp + 4);
            }
            uint4 wv;
            wv.x = f2bf2(v0.x, v0.y);
            wv.y = f2bf2(v0.z, v0.w);
            wv.z = f2bf2(v1.x, v1.y);
            wv.w = f2bf2(v1.z, v1.w);
            *(uint4*)&A[sr * 32 + (c ^ SWZ(sr))] = wv;
        }
        ushort* B = lds + 8192 + buf * 3072;
        #pragma unroll
        for (int f = tid; f < 384; f += 256) {
            int n = f >> 2, c = (f & 3) * 8;
            uint4 wv = *(const uint4*)&W1T[(size_t)n * DIN + k0 + c];
            *(uint4*)&B[n * 32 + (c ^ SWZ(n))] = wv;
        }
    };

    stage(0, 0);
    for (int kt = 0; kt < 16; ++kt) {
        __syncthreads();
        if (kt < 15) stage(kt + 1, (kt + 1) & 1);
        const int ab = (kt & 1) * 4096;
        const int bb = (kt & 1) * 3072;
        s8v b0 = *(s8v*)&lds[bof[0] + bb];
        s8v b1 = *(s8v*)&lds[bof[1] + bb];
        s8v b2 = *(s8v*)&lds[bof[2] + bb];
        #pragma unroll
        for (int i = 0; i < 4; ++i) {
            s8v a = *(s8v*)&lds[aof[i] + ab];
            acc[i][0] = __builtin_amdgcn_mfma_f32_16x16x32_bf16(a, b0, acc[i][0], 0, 0, 0);
            acc[i][1] = __builtin_amdgcn_mfma_f32_16x16x32_bf16(a, b1, acc[i][1], 0, 0, 0);
            acc[i][2] = __builtin_amdgcn_mfma_f32_16x16x32_bf16(a, b2, acc[i][2], 0, 0, 0);
        }
    }

    #pragma unroll
    for (int i = 0; i < 4; ++i) {
        int gr0 = row0 + rb + i * 16 + lq * 4;
        #pragma unroll
        for (int q = 0; q < 4; ++q) {
            int gr = gr0 + q;
            if (gr < N) {
                float di = dinv[gr];
                #pragma unroll
                for (int j = 0; j < 3; ++j)
                    hs1[(size_t)gr * DH + cb + j * 16 + lm] = f2bf(acc[i][j][q] * di);
            }
        }
    }
}

// ---------- agg1: wave per node, 8-deep gather ----------
__global__ __launch_bounds__(256) void k_agg1(
    const int* __restrict__ row_ptr, const int* __restrict__ adj,
    const float* __restrict__ dinv, const ushort* __restrict__ hs1,
    const float* __restrict__ b1, ushort* __restrict__ h1, int N)
{
    int t = blockIdx.x * 256 + threadIdx.x;
    int node = t >> 6, lane = t & 63;
    if (node >= N) return;
    int c = lane << 1;
    const bool act = (c < DH);

    float a0 = 0.f, a1 = 0.f;
    if (act) {
        uint u = *(const uint*)&hs1[(size_t)node * DH + c];   // self-loop
        a0 = bflo(u); a1 = bfhi(u);
    }
    int e = row_ptr[node], e1 = row_ptr[node + 1];
    for (; e + 7 < e1; e += 8) {
        int s0 = adj[e],     s1 = adj[e + 1], s2 = adj[e + 2], s3 = adj[e + 3];
        int s4 = adj[e + 4], s5 = adj[e + 5], s6 = adj[e + 6], s7 = adj[e + 7];
        if (act) {
            uint u0 = *(const uint*)&hs1[(size_t)s0 * DH + c];
            uint u1 = *(const uint*)&hs1[(size_t)s1 * DH + c];
            uint u2 = *(const uint*)&hs1[(size_t)s2 * DH + c];
            uint u3 = *(const uint*)&hs1[(size_t)s3 * DH + c];
            uint u4 = *(const uint*)&hs1[(size_t)s4 * DH + c];
            uint u5 = *(const uint*)&hs1[(size_t)s5 * DH + c];
            uint u6 = *(const uint*)&hs1[(size_t)s6 * DH + c];
            uint u7 = *(const uint*)&hs1[(size_t)s7 * DH + c];
            a0 += bflo(u0); a1 += bfhi(u0);
            a0 += bflo(u1); a1 += bfhi(u1);
            a0 += bflo(u2); a1 += bfhi(u2);
            a0 += bflo(u3); a1 += bfhi(u3);
            a0 += bflo(u4); a1 += bfhi(u4);
            a0 += bflo(u5); a1 += bfhi(u5);
            a0 += bflo(u6); a1 += bfhi(u6);
            a0 += bflo(u7); a1 += bfhi(u7);
        }
    }
    for (; e < e1; ++e) {
        int s = adj[e];
        if (act) {
            uint u = *(const uint*)&hs1[(size_t)s * DH + c];
            a0 += bflo(u); a1 += bfhi(u);
        }
    }
    if (act) {
        float di = dinv[node];
        float r0 = fmaxf(fmaf(a0, di, b1[c]), 0.f);
        float r1 = fmaxf(fmaf(a1, di, b1[c + 1]), 0.f);
        *(uint*)&h1[(size_t)node * DH + c] = f2bf2(r0, r1);
    }
}

// ---------- GEMM2 (MFMA bf16): hs2b = bf16((h1 @ W2) * dinv), row stride 64 (128B lines) ----------
__global__ __launch_bounds__(256) void k_gemm2(
    const ushort* __restrict__ h1, const ushort* __restrict__ W2T,
    const float* __restrict__ dinv, ushort* __restrict__ hs2b, int N)
{
    __shared__ __align__(16) ushort lds[16384 + 48 * 128];
    const int tid = threadIdx.x;
    const int row0 = blockIdx.x * 128;

    for (int f = tid; f < 576; f += 256) {
        int r = f / 12, c = (f % 12) * 8;
        uint4 v = *(const uint4*)&W2T[r * DH + c];
        *(uint4*)&lds[16384 + r * 128 + (c ^ ((r & 7) << 3))] = v;
    }
    {
        int r = tid >> 1, half = tid & 1;
        int gr = row0 + r;
        #pragma unroll
        for (int i = 0; i < 6; ++i) {
            int c = half * 48 + i * 8;
            uint4 v = make_uint4(0, 0, 0, 0);
            if (gr < N) v = *(const uint4*)&h1[(size_t)gr * DH + c];
            *(uint4*)&lds[r * 128 + (c ^ ((r & 7) << 3))] = v;
        }
    }
    __syncthreads();

    const int lane = tid & 63, w = tid >> 6;
    const int rb = w * 32, lm = lane & 15, lq = lane >> 4;
    f4v acc[2][3];
    #pragma unroll
    for (int i = 0; i < 2; ++i)
        #pragma unroll
        for (int j = 0; j < 3; ++j) acc[i][j] = (f4v)0.f;

    #pragma unroll
    for (int ks = 0; ks < 3; ++ks) {
        int kk = ks * 32 + lq * 8;
        s8v b[3];
        #pragma unroll
        for (int j = 0; j < 3; ++j) {
            int n = j * 16 + lm;
            b[j] = *(s8v*)&lds[16384 + n * 128 + (kk ^ ((n & 7) << 3))];
        }
        #pragma unroll
        for (int i = 0; i < 2; ++i) {
            int r = rb + i * 16 + lm;
            s8v a = *(s8v*)&lds[r * 128 + (kk ^ ((r & 7) << 3))];
            #pragma unroll
            for (int j = 0; j < 3; ++j)
                acc[i][j] = __builtin_amdgcn_mfma_f32_16x16x32_bf16(a, b[j], acc[i][j], 0, 0, 0);
        }
    }

    #pragma unroll
    for (int i = 0; i < 2; ++i) {
        int gr0 = row0 + rb + i * 16 + lq * 4;
        #pragma unroll
        for (int q = 0; q < 4; ++q) {
            int gr = gr0 + q;
            if (gr < N) {
                float di = dinv[gr];
                #pragma unroll
                for (int j = 0; j < 3; ++j) {
                    int col = j * 16 + lm;
                    if (col < DOUT)
                        hs2b[(size_t)gr * 64 + col] = f2bf(acc[i][j][q] * di);
                }
            }
        }
    }
}

// ---------- agg2 + bias + log_softmax fused: wave/node, 1 cache line per edge ----------
__global__ __launch_bounds__(256) void k_agg2sm(
    const int* __restrict__ row_ptr, const int* __restrict__ adj,
    const float* __restrict__ dinv, const ushort* __restrict__ hs2b,
    const float* __restrict__ b2, float* __restrict__ out,
    float* __restrict__ lsm, int N)
{
    int t = blockIdx.x * 256 + threadIdx.x;
    int node = t >> 6, lane = t & 63;
    if (node >= N) return;
    int c = lane << 1;
    const bool act = (c < DOUT);   // lanes 0..19

    float a0 = 0.f, a1 = 0.f;
    if (act) {
        uint u = *(const uint*)&hs2b[(size_t)node * 64 + c];   // self-loop
        a0 = bflo(u); a1 = bfhi(u);
    }
    int e = row_ptr[node], e1 = row_ptr[node + 1];
    for (; e + 7 < e1; e += 8) {
        int s0 = adj[e],     s1 = adj[e + 1], s2 = adj[e + 2], s3 = adj[e + 3];
        int s4 = adj[e + 4], s5 = adj[e + 5], s6 = adj[e + 6], s7 = adj[e + 7];
        if (act) {
            uint u0 = *(const uint*)&hs2b[(size_t)s0 * 64 + c];
            uint u1 = *(const uint*)&hs2b[(size_t)s1 * 64 + c];
            uint u2 = *(const uint*)&hs2b[(size_t)s2 * 64 + c];
            uint u3 = *(const uint*)&hs2b[(size_t)s3 * 64 + c];
            uint u4 = *(const uint*)&hs2b[(size_t)s4 * 64 + c];
            uint u5 = *(const uint*)&hs2b[(size_t)s5 * 64 + c];
            uint u6 = *(const uint*)&hs2b[(size_t)s6 * 64 + c];
            uint u7 = *(const uint*)&hs2b[(size_t)s7 * 64 + c];
            a0 += bflo(u0); a1 += bfhi(u0);
            a0 += bflo(u1); a1 += bfhi(u1);
            a0 += bflo(u2); a1 += bfhi(u2);
            a0 += bflo(u3); a1 += bfhi(u3);
            a0 += bflo(u4); a1 += bfhi(u4);
            a0 += bflo(u5); a1 += bfhi(u5);
            a0 += bflo(u6); a1 += bfhi(u6);
            a0 += bflo(u7); a1 += bfhi(u7);
        }
    }
    for (; e < e1; ++e) {
        int s = adj[e];
        if (act) {
            uint u = *(const uint*)&hs2b[(size_t)s * 64 + c];
            a0 += bflo(u); a1 += bfhi(u);
        }
    }

    float di = act ? dinv[node] : 0.f;
    float v0 = act ? fmaf(a0, di, b2[c]) : -1e30f;
    float v1 = act ? fmaf(a1, di, b2[c + 1]) : -1e30f;
    float m = fmaxf(v0, v1);
    #pragma unroll
    for (int off = 32; off >= 1; off >>= 1) m = fmaxf(m, __shfl_xor(m, off));
    float ex = act ? (__expf(v0 - m) + __expf(v1 - m)) : 0.f;
    float s = ex;
    #pragma unroll
    for (int off = 32; off >= 1; off >>= 1) s += __shfl_xor(s, off);
    float lse = m + __logf(s);
    if (act) {
        *(float2*)&out[(size_t)node * DOUT + c] = make_float2(v0, v1);
        *(float2*)&lsm[(size_t)node * DOUT + c] = make_float2(v0 - lse, v1 - lse);
    }
}

extern "C" void kernel_launch(void* const* d_in, const int* in_sizes, int n_in,
                              void* d_out, int out_size, void* d_ws, size_t ws_size,
                              hipStream_t stream) {
    const float* x  = (const float*)d_in[0];
    const int*   ei = (const int*)d_in[1];
    const float* W1 = (const float*)d_in[2];
    const float* b1 = (const float*)d_in[3];
    const float* W2 = (const float*)d_in[4];
    const float* b2 = (const float*)d_in[5];

    const int N = in_sizes[0] / DIN;
    const int E = in_sizes[1] / 2;
    const int* srcp = ei;
    const int* dstp = ei + E;
    const int SB = (N + 255) / 256;

    ushort* hs1  = (ushort*)d_ws;                   // N*96 bf16
    ushort* h1   = hs1 + (size_t)N * DH;            // N*96 bf16
    ushort* hs2b = h1 + (size_t)N * DH;             // N*64 bf16 (40 used, 128B rows)
    float* dinv  = (float*)(hs2b + (size_t)N * 64); // N
    ushort* W1T  = (ushort*)(dinv + N);             // 96*512 bf16
    ushort* W2T  = W1T + (size_t)DH * DIN;          // 48*96 bf16
    int* cnt     = (int*)(W2T + 48 * DH);           // N
    int* row_ptr = cnt + N;                         // N+1
    int* adj     = row_ptr + N + 1;                 // E
    int* pos     = adj + E;                         // E
    int* bsum    = pos + E;                         // SB
    int* boff    = bsum + SB;                       // SB

    float* out = (float*)d_out;                     // logits [N*40]
    float* lsm = out + (size_t)N * DOUT;            // log_softmax [N*40]

    const int gE = (E + 255) / 256;

    k_prep<<<SB, 256, 0, stream>>>(W1, W2, cnt, W1T, W2T, N);
    k_hist<<<gE, 256, 0, stream>>>(dstp, cnt, pos, E);
    k_blocksum<<<SB, 256, 0, stream>>>(cnt, bsum, N);
    k_scan_small<<<1, 256, 0, stream>>>(bsum, boff, SB);
    k_rowptr<<<SB, 256, 0, stream>>>(cnt, boff, row_ptr, dinv, N);
    k_fill<<<gE, 256, 0, stream>>>(srcp, dstp, row_ptr, pos, adj, E);

    k_gemm1<<<(N + 127) / 128, 256, 0, stream>>>(x, W1T, dinv, hs1, N);
    k_agg1<<<(int)(((size_t)N * 64 + 255) / 256), 256, 0, stream>>>(row_ptr, adj, dinv, hs1, b1, h1, N);

    k_gemm2<<<(N + 127) / 128, 256, 0, stream>>>(h1, W2T, dinv, hs2b, N);
    k_agg2sm<<<(int)(((size_t)N * 64 + 255) / 256), 256, 0, stream>>>(row_ptr, adj, dinv, hs2b, b2, out, lsm, N);
}